// Round 7
// baseline (98.415 us; speedup 1.0000x reference)
//
#include <hip/hip_runtime.h>

typedef unsigned short u16;
typedef unsigned int   u32;
typedef __bf16  bf16x8 __attribute__((ext_vector_type(8)));
typedef float   f32x16 __attribute__((ext_vector_type(16)));
typedef u32     u32x4  __attribute__((ext_vector_type(4)));

#define NN  4096
#define CCH 64
#define CQ  32
#define K1S 0.0225421092623961f   // log2(e)/64  (folded into q)

__device__ __forceinline__ u16 bfc(float a) { return __builtin_bit_cast(u16, (__bf16)a); }

// exp2 + pack pair to bf16x2 in 3 instructions
__device__ __forceinline__ u32 e2pk(float a, float b) {
  float ea, eb; u32 r;
  asm("v_exp_f32 %0, %1" : "=v"(ea) : "v"(a));
  asm("v_exp_f32 %0, %1" : "=v"(eb) : "v"(b));
  asm("v_cvt_pk_bf16_f32 %0, %1, %2" : "=v"(r) : "v"(ea), "v"(eb));
  return r;
}

__device__ __forceinline__ void gload16(const void* g, void* l) {
  __builtin_amdgcn_global_load_lds((const __attribute__((address_space(1))) void*)g,
                                   (__attribute__((address_space(3))) void*)l, 16, 0, 0);
}

// Image layouts (per 64-key chunk), frag-major so attn LDS reads are lane-linear:
//  K image 4KB: region(s,ks)=s*2+ks (1KB); lane l=h*32+r31: K[key=s*32+r31][ck=ks*16+8h+{0..7}]
//  V image 8KB: region(s,kb,ct)=s*4+kb*2+ct (1KB); lane l: V[c=ct*32+r31][key=s*32+kb*16+4h+{0..3,8..11}]

// ---- kernel 1: 1x1 convs (wave-uniform weights -> scalar loads), 8 waves/block
__global__ __launch_bounds__(512) void qkv_kernel(
    const float* __restrict__ x,
    const float* __restrict__ wq, const float* __restrict__ bq,
    const float* __restrict__ wk, const float* __restrict__ bk,
    const float* __restrict__ wv, const float* __restrict__ bv,
    u16* __restrict__ qT, char* __restrict__ kws, char* __restrict__ vws)
{
  __shared__ u16 qls[64][34];
  __shared__ u16 kls[64][34];
  __shared__ u16 vls[64][66];
  const int bid = blockIdx.x;
  const int b = bid >> 6;
  const int chunk = bid & 63;
  const int nbase = chunk * 64;
  const int t = threadIdx.x, lane = t & 63, wid = t >> 6;

  const float* xb = x + (size_t)b * CCH * NN + nbase + lane;
  float xcol[64];
  #pragma unroll
  for (int c = 0; c < 64; ++c) xcol[c] = xb[(size_t)c * NN];

  // 8 waves x 16 outputs: wid0,1=q; wid2,3=k; wid4..7=v
  const float* w; const float* bias; float sc = 1.0f;
  const int sub = (wid & 1) * 16;
  if (wid < 2)      { w = wq + sub * 64; bias = bq + sub; sc = K1S; }
  else if (wid < 4) { w = wk + sub * 64; bias = bk + sub; }
  else              { w = wv + (wid - 4) * 16 * 64; bias = bv + (wid - 4) * 16; }

  for (int i = 0; i < 16; ++i) {
    float a = bias[i];
    #pragma unroll
    for (int c = 0; c < 64; ++c) a = fmaf(w[i * 64 + c], xcol[c], a);
    a *= sc;
    u16 hv = bfc(a);
    if (wid < 2)      qls[lane][sub + i] = hv;
    else if (wid < 4) kls[lane][sub + i] = hv;
    else              vls[(wid - 4) * 16 + i][lane] = hv;
  }
  __syncthreads();

  u32* qdst = (u32*)(qT + ((size_t)b * NN + nbase) * CQ);
  #pragma unroll
  for (int jj = 0; jj < 2; ++jj) {
    int i = t + 512 * jj;
    int n = i >> 4, cp = i & 15;
    qdst[i] = *(const u32*)&qls[n][cp * 2];
  }
  u32* kimg = (u32*)(kws + ((size_t)b * 64 + chunk) * 4096);
  #pragma unroll
  for (int jj = 0; jj < 2; ++jj) {
    int i = t + 512 * jj;
    int reg = i >> 8, l = (i >> 2) & 63, j2 = i & 3;
    int s = reg >> 1, ks = reg & 1;
    int key = s * 32 + (l & 31);
    int ck  = ks * 16 + (l >> 5) * 8 + j2 * 2;
    kimg[i] = *(const u32*)&kls[key][ck];
  }
  u32* vimg = (u32*)(vws + ((size_t)b * 64 + chunk) * 8192);
  #pragma unroll
  for (int jj = 0; jj < 4; ++jj) {
    int i = t + 512 * jj;
    int reg = i >> 8, l = (i >> 2) & 63, j2 = i & 3;
    int s = reg >> 2, kb = (reg >> 1) & 1, ct = reg & 1;
    int c   = ct * 32 + (l & 31);
    int key = s * 32 + kb * 16 + (l >> 5) * 4 + (j2 >> 1) * 8 + (j2 & 1) * 2;
    vimg[i] = *(const u32*)&vls[c][key];
  }
}

// ---- kernel 2: flash attention, triple-buffered K/V, counted vmcnt + raw barrier
template<int NSPLIT>
__global__ __launch_bounds__(256, 2) void attn_kernel(
    const u16* __restrict__ qT, const char* __restrict__ kws, const char* __restrict__ vws,
    u32* __restrict__ opart, float* __restrict__ lpart)
{
  constexpr int CH = 64 / NSPLIT;   // 64-key chunks per split
  __shared__ __align__(16) char kbuf[3][4096];
  __shared__ __align__(16) char vbuf[3][8192];
  const int bid = blockIdx.x;
  const int b = bid & 7, qt = (bid >> 3) & 15, split = bid >> 7;  // qt: 256-query tile
  const int t = threadIdx.x, lane = t & 63, wid = t >> 6;
  const int h = lane >> 5, c31 = lane & 31;

  // wave covers queries [qt*256 + wid*64, +64): tiles A (+0) and B (+32)
  const u16* qpA = qT + ((size_t)b * NN + qt * 256 + wid * 64 + c31) * CQ + h * 8;
  const bf16x8 qfA0 = *(const bf16x8*)(qpA);
  const bf16x8 qfA1 = *(const bf16x8*)(qpA + 16);
  const bf16x8 qfB0 = *(const bf16x8*)(qpA + 32 * CQ);
  const bf16x8 qfB1 = *(const bf16x8*)(qpA + 32 * CQ + 16);

  const char* ksrc = kws + ((size_t)b * 64 + split * CH) * 4096 + t * 16;
  const char* vsrc = vws + ((size_t)b * 64 + split * CH) * 8192 + t * 16;

  auto stage = [&](int buf, int it) {
    gload16(ksrc + (size_t)it * 4096, &kbuf[buf][wid * 1024]);
    gload16(vsrc + (size_t)it * 8192, &vbuf[buf][wid * 1024]);
    gload16(vsrc + (size_t)it * 8192 + 4096, &vbuf[buf][4096 + wid * 1024]);
  };

  const bf16x8 onef = __builtin_bit_cast(bf16x8,
      (u32x4){0x3F803F80u, 0x3F803F80u, 0x3F803F80u, 0x3F803F80u});

  f32x16 accA0 = {}, accA1 = {}, accB0 = {}, accB1 = {}, laccA = {}, laccB = {};
  const int lofs = lane * 16;

  stage(0, 0);
  stage(1, 1);

  #pragma unroll
  for (int it = 0; it < CH; ++it) {
    // wait own stage(it) loads (3 newest = stage(it+1) may stay in flight)
    if (it == CH - 1) asm volatile("s_waitcnt vmcnt(0)" ::: "memory");
    else              asm volatile("s_waitcnt vmcnt(3)" ::: "memory");
    __builtin_amdgcn_s_barrier();     // all waves' stage(it) complete; all done reading buf[(it+2)%3]
    __builtin_amdgcn_sched_barrier(0);
    if (it + 2 < CH) stage((it + 2) % 3, it + 2);
    const int cur = it % 3;

    // K frags loaded ONCE, reused by both q-tiles
    const bf16x8 kf0 = *(const bf16x8*)&kbuf[cur][lofs];
    const bf16x8 kf1 = *(const bf16x8*)&kbuf[cur][1024 + lofs];
    const bf16x8 kf2 = *(const bf16x8*)&kbuf[cur][2048 + lofs];
    const bf16x8 kf3 = *(const bf16x8*)&kbuf[cur][3072 + lofs];

    f32x16 sA0, sA1, sB0, sB1;
    __builtin_amdgcn_s_setprio(1);
    sA0 = __builtin_amdgcn_mfma_f32_32x32x16_bf16(kf0, qfA0, (f32x16){}, 0, 0, 0);
    sA0 = __builtin_amdgcn_mfma_f32_32x32x16_bf16(kf1, qfA1, sA0, 0, 0, 0);
    sA1 = __builtin_amdgcn_mfma_f32_32x32x16_bf16(kf2, qfA0, (f32x16){}, 0, 0, 0);
    sA1 = __builtin_amdgcn_mfma_f32_32x32x16_bf16(kf3, qfA1, sA1, 0, 0, 0);
    sB0 = __builtin_amdgcn_mfma_f32_32x32x16_bf16(kf0, qfB0, (f32x16){}, 0, 0, 0);
    sB0 = __builtin_amdgcn_mfma_f32_32x32x16_bf16(kf1, qfB1, sB0, 0, 0, 0);
    sB1 = __builtin_amdgcn_mfma_f32_32x32x16_bf16(kf2, qfB0, (f32x16){}, 0, 0, 0);
    sB1 = __builtin_amdgcn_mfma_f32_32x32x16_bf16(kf3, qfB1, sB1, 0, 0, 0);
    __builtin_amdgcn_s_setprio(0);

    // P = exp2(S), packed; regs already in PV B-frag order
    u32 pwA[16] __attribute__((aligned(16)));
    u32 pwB[16] __attribute__((aligned(16)));
    #pragma unroll
    for (int r = 0; r < 16; r += 2) {
      pwA[r >> 1]       = e2pk(sA0[r], sA0[r + 1]);
      pwA[8 + (r >> 1)] = e2pk(sA1[r], sA1[r + 1]);
      pwB[r >> 1]       = e2pk(sB0[r], sB0[r + 1]);
      pwB[8 + (r >> 1)] = e2pk(sB1[r], sB1[r + 1]);
    }

    // O += V . P^T ; l += 1 . P^T   (V frags loaded once, reused by both q-tiles)
    __builtin_amdgcn_s_setprio(1);
    #pragma unroll
    for (int s = 0; s < 2; ++s) {
      #pragma unroll
      for (int kb = 0; kb < 2; ++kb) {
        const bf16x8 pfA = __builtin_bit_cast(bf16x8, *(const u32x4*)&pwA[s * 8 + kb * 4]);
        const bf16x8 pfB = __builtin_bit_cast(bf16x8, *(const u32x4*)&pwB[s * 8 + kb * 4]);
        const bf16x8 vf0 = *(const bf16x8*)&vbuf[cur][(s * 4 + kb * 2) * 1024 + lofs];
        const bf16x8 vf1 = *(const bf16x8*)&vbuf[cur][(s * 4 + kb * 2 + 1) * 1024 + lofs];
        accA0 = __builtin_amdgcn_mfma_f32_32x32x16_bf16(vf0, pfA, accA0, 0, 0, 0);
        accA1 = __builtin_amdgcn_mfma_f32_32x32x16_bf16(vf1, pfA, accA1, 0, 0, 0);
        accB0 = __builtin_amdgcn_mfma_f32_32x32x16_bf16(vf0, pfB, accB0, 0, 0, 0);
        accB1 = __builtin_amdgcn_mfma_f32_32x32x16_bf16(vf1, pfB, accB1, 0, 0, 0);
        laccA = __builtin_amdgcn_mfma_f32_32x32x16_bf16(onef, pfA, laccA, 0, 0, 0);
        laccB = __builtin_amdgcn_mfma_f32_32x32x16_bf16(onef, pfB, laccB, 0, 0, 0);
      }
    }
    __builtin_amdgcn_s_setprio(0);
  }

  // opart[(b,qt128)*NSPLIT+split][cp(32)][q(128)], bf16-packed channel pairs
  const int qt128 = qt * 2 + (wid >> 1);
  const size_t obase = ((size_t)(b * 32 + qt128) * NSPLIT + split) * 4096;
  #pragma unroll
  for (int j = 0; j < 2; ++j) {
    const int col = (wid & 1) * 64 + j * 32 + c31;
    #pragma unroll
    for (int ct = 0; ct < 2; ++ct) {
      const f32x16& a = j ? (ct ? accB1 : accB0) : (ct ? accA1 : accA0);
      #pragma unroll
      for (int g2 = 0; g2 < 4; ++g2) {
        #pragma unroll
        for (int b2 = 0; b2 < 2; ++b2) {
          int cp = ct * 16 + g2 * 4 + h * 2 + b2;
          float lo = a[g2 * 4 + b2 * 2], hi = a[g2 * 4 + b2 * 2 + 1];
          u32 pr; asm("v_cvt_pk_bf16_f32 %0, %1, %2" : "=v"(pr) : "v"(lo), "v"(hi));
          opart[obase + cp * 128 + col] = pr;
        }
      }
    }
    if (h == 0) {
      const f32x16& l = j ? laccB : laccA;
      lpart[((size_t)(b * 32 + qt128) * NSPLIT + split) * 128 + col] = l[0];
    }
  }
}

// ---- kernel 3: combine splits + normalize + fused final conv + residual
// 512 threads: 8 waves x 8 outputs (wave-uniform weights), 64 queries/block
template<int NSPLIT>
__global__ __launch_bounds__(512) void combine_kernel(
    const u32* __restrict__ opart, const float* __restrict__ lpart,
    const float* __restrict__ x, const float* __restrict__ wf, const float* __restrict__ bfb,
    const float* __restrict__ gamma, float* __restrict__ out)
{
  __shared__ float ols[64][65];
  __shared__ float linv[64];
  const int bid = blockIdx.x;
  const int b = bid & 7, qt64 = bid >> 3;
  const int qt128 = qt64 >> 1, qh = qt64 & 1;
  const int t = threadIdx.x, lane = t & 63, wid = t >> 6;

  const u32* ob = opart + (size_t)(b * 32 + qt128) * NSPLIT * 4096 + qh * 64;
  #pragma unroll
  for (int jj = 0; jj < 4; ++jj) {
    int i = t + 512 * jj;
    int cp = i >> 6, q = i & 63;
    float lo = 0.f, hi = 0.f;
    #pragma unroll
    for (int s = 0; s < NSPLIT; ++s) {
      u32 a = ob[s * 4096 + cp * 128 + q];
      lo += __builtin_bit_cast(float, (a << 16));
      hi += __builtin_bit_cast(float, (a & 0xffff0000u));
    }
    ols[cp * 2][q]     = lo;
    ols[cp * 2 + 1][q] = hi;
  }
  if (t < 64) {
    const float* lp = lpart + (size_t)(b * 32 + qt128) * NSPLIT * 128 + qh * 64;
    float l = 0.f;
    #pragma unroll
    for (int s = 0; s < NSPLIT; ++s) l += lp[s * 128 + t];
    linv[t] = 1.f / l;
  }
  __syncthreads();

  const float oinv = linv[lane];
  float oc[64];
  #pragma unroll
  for (int c = 0; c < 64; ++c) oc[c] = ols[c][lane] * oinv;
  const float gm = gamma[0];
  const size_t nidx = (size_t)qt64 * 64 + lane;
  #pragma unroll
  for (int i = 0; i < 8; ++i) {
    const int o = wid * 8 + i;
    float a = bfb[o];
    #pragma unroll
    for (int c = 0; c < 64; ++c) a = fmaf(wf[o * 64 + c], oc[c], a);
    const size_t idx = ((size_t)b * CCH + o) * NN + nidx;
    out[idx] = gm * a + x[idx];
  }
}

extern "C" void kernel_launch(void* const* d_in, const int* in_sizes, int n_in,
                              void* d_out, int out_size, void* d_ws, size_t ws_size,
                              hipStream_t stream) {
  const float* x     = (const float*)d_in[0];
  const float* wq    = (const float*)d_in[1];
  const float* bq    = (const float*)d_in[2];
  const float* wk    = (const float*)d_in[3];
  const float* bk    = (const float*)d_in[4];
  const float* wv    = (const float*)d_in[5];
  const float* bv    = (const float*)d_in[6];
  const float* wf    = (const float*)d_in[7];
  const float* bf_   = (const float*)d_in[8];
  const float* gamma = (const float*)d_in[9];
  float* out = (float*)d_out;

  u16* qT   = (u16*)d_ws;                                   // 2 MB
  char* kws = (char*)(qT + (size_t)8 * NN * CQ);            // 2 MB
  char* vws = kws + (size_t)8 * 64 * 4096;                  // 4 MB
  u32* opart = (u32*)(vws + (size_t)8 * 64 * 8192);
  const size_t base = 2097152ull + 2097152ull + 4194304ull;
  const size_t need8 = base + 8ull * (4194304ull + 131072ull);
  const size_t need4 = base + 4ull * (4194304ull + 131072ull);

  qkv_kernel<<<dim3(512), dim3(512), 0, stream>>>(x, wq, bq, wk, bk, wv, bv, qT, kws, vws);
  if (ws_size >= need8) {
    float* lpart = (float*)(opart + (size_t)8 * 32 * 8 * 4096);
    attn_kernel<8><<<dim3(1024), dim3(256), 0, stream>>>(qT, kws, vws, opart, lpart);
    combine_kernel<8><<<dim3(512), dim3(512), 0, stream>>>(opart, lpart, x, wf, bf_, gamma, out);
  } else if (ws_size >= need4) {
    float* lpart = (float*)(opart + (size_t)8 * 32 * 4 * 4096);
    attn_kernel<4><<<dim3(512), dim3(256), 0, stream>>>(qT, kws, vws, opart, lpart);
    combine_kernel<4><<<dim3(512), dim3(512), 0, stream>>>(opart, lpart, x, wf, bf_, gamma, out);
  } else {
    float* lpart = (float*)(opart + (size_t)8 * 32 * 2 * 4096);
    attn_kernel<2><<<dim3(256), dim3(256), 0, stream>>>(qT, kws, vws, opart, lpart);
    combine_kernel<2><<<dim3(512), dim3(512), 0, stream>>>(opart, lpart, x, wf, bf_, gamma, out);
  }
}

// Round 8
// 90.024 us; speedup vs baseline: 1.0932x; 1.0932x over previous
//
#include <hip/hip_runtime.h>

typedef unsigned short u16;
typedef unsigned int   u32;
typedef __bf16  bf16x8 __attribute__((ext_vector_type(8)));
typedef float   f32x16 __attribute__((ext_vector_type(16)));
typedef u32     u32x4  __attribute__((ext_vector_type(4)));

#define NN  4096
#define CCH 64
#define CQ  32
#define K1S 0.0225421092623961f   // log2(e)/64  (folded into q)

__device__ __forceinline__ u16 bfc(float a) { return __builtin_bit_cast(u16, (__bf16)a); }

// exp2 + pack pair to bf16x2 in 3 instructions
__device__ __forceinline__ u32 e2pk(float a, float b) {
  float ea, eb; u32 r;
  asm("v_exp_f32 %0, %1" : "=v"(ea) : "v"(a));
  asm("v_exp_f32 %0, %1" : "=v"(eb) : "v"(b));
  asm("v_cvt_pk_bf16_f32 %0, %1, %2" : "=v"(r) : "v"(ea), "v"(eb));
  return r;
}

__device__ __forceinline__ void gload16(const void* g, void* l) {
  __builtin_amdgcn_global_load_lds((const __attribute__((address_space(1))) void*)g,
                                   (__attribute__((address_space(3))) void*)l, 16, 0, 0);
}

// Image layouts (per 64-key chunk), frag-major so attn LDS reads are lane-linear:
//  K image 4KB: region(s,ks)=s*2+ks (1KB); lane l=h*32+r31: K[key=s*32+r31][ck=ks*16+8h+{0..7}]
//  V image 8KB: region(s,kb,ct)=s*4+kb*2+ct (1KB); lane l: V[c=ct*32+r31][key=s*32+kb*16+4h+{0..3,8..11}]

// ---- kernel 1: 1x1 convs; x tile staged ONCE in LDS (was 8x redundant global reads)
__global__ __launch_bounds__(512) void qkv_kernel(
    const float* __restrict__ x,
    const float* __restrict__ wq, const float* __restrict__ bq,
    const float* __restrict__ wk, const float* __restrict__ bk,
    const float* __restrict__ wv, const float* __restrict__ bv,
    u16* __restrict__ qT, char* __restrict__ kws, char* __restrict__ vws)
{
  __shared__ float xs[64][64];
  __shared__ u16 qls[64][34];
  __shared__ u16 kls[64][34];
  __shared__ u16 vls[64][66];
  const int bid = blockIdx.x;
  const int b = bid >> 6;
  const int chunk = bid & 63;
  const int nbase = chunk * 64;
  const int t = threadIdx.x, lane = t & 63, wid = t >> 6;

  // stage x tile [64c][64n] coalesced (each row: 8 threads x 2 float4)
  {
    const float* xb = x + (size_t)b * CCH * NN + nbase;
    const int row = t >> 3, colq = (t & 7) * 2;
    float4 v0 = *(const float4*)(xb + (size_t)row * NN + colq * 4);
    float4 v1 = *(const float4*)(xb + (size_t)row * NN + colq * 4 + 4);
    float4* dst = (float4*)&xs[0][0];
    dst[row * 16 + colq]     = v0;
    dst[row * 16 + colq + 1] = v1;
  }
  __syncthreads();

  // xcol from LDS: lane-indexed -> 2-way bank alias (free)
  float xcol[64];
  #pragma unroll
  for (int c = 0; c < 64; ++c) xcol[c] = xs[c][lane];

  // 8 waves x 16 outputs: wid0,1=q; wid2,3=k; wid4..7=v (wave-uniform w -> scalar loads)
  const float* w; const float* bias; float sc = 1.0f;
  const int sub = (wid & 1) * 16;
  if (wid < 2)      { w = wq + sub * 64; bias = bq + sub; sc = K1S; }
  else if (wid < 4) { w = wk + sub * 64; bias = bk + sub; }
  else              { w = wv + (wid - 4) * 16 * 64; bias = bv + (wid - 4) * 16; }

  #pragma unroll 2
  for (int i = 0; i < 16; ++i) {
    float a = bias[i];
    #pragma unroll
    for (int c = 0; c < 64; ++c) a = fmaf(w[i * 64 + c], xcol[c], a);
    a *= sc;
    u16 hv = bfc(a);
    if (wid < 2)      qls[lane][sub + i] = hv;
    else if (wid < 4) kls[lane][sub + i] = hv;
    else              vls[(wid - 4) * 16 + i][lane] = hv;
  }
  __syncthreads();

  u32* qdst = (u32*)(qT + ((size_t)b * NN + nbase) * CQ);
  #pragma unroll
  for (int jj = 0; jj < 2; ++jj) {
    int i = t + 512 * jj;
    int n = i >> 4, cp = i & 15;
    qdst[i] = *(const u32*)&qls[n][cp * 2];
  }
  u32* kimg = (u32*)(kws + ((size_t)b * 64 + chunk) * 4096);
  #pragma unroll
  for (int jj = 0; jj < 2; ++jj) {
    int i = t + 512 * jj;
    int reg = i >> 8, l = (i >> 2) & 63, j2 = i & 3;
    int s = reg >> 1, ks = reg & 1;
    int key = s * 32 + (l & 31);
    int ck  = ks * 16 + (l >> 5) * 8 + j2 * 2;
    kimg[i] = *(const u32*)&kls[key][ck];
  }
  u32* vimg = (u32*)(vws + ((size_t)b * 64 + chunk) * 8192);
  #pragma unroll
  for (int jj = 0; jj < 4; ++jj) {
    int i = t + 512 * jj;
    int reg = i >> 8, l = (i >> 2) & 63, j2 = i & 3;
    int s = reg >> 2, kb = (reg >> 1) & 1, ct = reg & 1;
    int c   = ct * 32 + (l & 31);
    int key = s * 32 + kb * 16 + (l >> 5) * 4 + (j2 >> 1) * 8 + (j2 & 1) * 2;
    vimg[i] = *(const u32*)&vls[c][key];
  }
}

// ---- kernel 2: flash attention, triple-buffered K/V, counted vmcnt + raw barrier
template<int NSPLIT>
__global__ __launch_bounds__(256, 2) void attn_kernel(
    const u16* __restrict__ qT, const char* __restrict__ kws, const char* __restrict__ vws,
    u32* __restrict__ opart, float* __restrict__ lpart)
{
  constexpr int CH = 64 / NSPLIT;   // 64-key chunks per split
  __shared__ __align__(16) char kbuf[3][4096];
  __shared__ __align__(16) char vbuf[3][8192];
  const int bid = blockIdx.x;
  const int b = bid & 7, qt = (bid >> 3) & 15, split = bid >> 7;  // qt: 256-query tile
  const int t = threadIdx.x, lane = t & 63, wid = t >> 6;
  const int h = lane >> 5, c31 = lane & 31;

  // wave covers queries [qt*256 + wid*64, +64): tiles A (+0) and B (+32)
  const u16* qpA = qT + ((size_t)b * NN + qt * 256 + wid * 64 + c31) * CQ + h * 8;
  const bf16x8 qfA0 = *(const bf16x8*)(qpA);
  const bf16x8 qfA1 = *(const bf16x8*)(qpA + 16);
  const bf16x8 qfB0 = *(const bf16x8*)(qpA + 32 * CQ);
  const bf16x8 qfB1 = *(const bf16x8*)(qpA + 32 * CQ + 16);

  const char* ksrc = kws + ((size_t)b * 64 + split * CH) * 4096 + t * 16;
  const char* vsrc = vws + ((size_t)b * 64 + split * CH) * 8192 + t * 16;

  auto stage = [&](int buf, int it) {
    gload16(ksrc + (size_t)it * 4096, &kbuf[buf][wid * 1024]);
    gload16(vsrc + (size_t)it * 8192, &vbuf[buf][wid * 1024]);
    gload16(vsrc + (size_t)it * 8192 + 4096, &vbuf[buf][4096 + wid * 1024]);
  };

  const bf16x8 onef = __builtin_bit_cast(bf16x8,
      (u32x4){0x3F803F80u, 0x3F803F80u, 0x3F803F80u, 0x3F803F80u});

  f32x16 accA0 = {}, accA1 = {}, accB0 = {}, accB1 = {}, laccA = {}, laccB = {};
  const int lofs = lane * 16;

  stage(0, 0);
  stage(1, 1);

  #pragma unroll
  for (int it = 0; it < CH; ++it) {
    // wait own stage(it) loads (3 newest = stage(it+1) may stay in flight)
    if (it == CH - 1) asm volatile("s_waitcnt vmcnt(0)" ::: "memory");
    else              asm volatile("s_waitcnt vmcnt(3)" ::: "memory");
    __builtin_amdgcn_s_barrier();     // all waves' stage(it) complete; all done reading buf[(it+2)%3]
    __builtin_amdgcn_sched_barrier(0);
    if (it + 2 < CH) stage((it + 2) % 3, it + 2);
    const int cur = it % 3;

    // K frags loaded ONCE, reused by both q-tiles
    const bf16x8 kf0 = *(const bf16x8*)&kbuf[cur][lofs];
    const bf16x8 kf1 = *(const bf16x8*)&kbuf[cur][1024 + lofs];
    const bf16x8 kf2 = *(const bf16x8*)&kbuf[cur][2048 + lofs];
    const bf16x8 kf3 = *(const bf16x8*)&kbuf[cur][3072 + lofs];

    f32x16 sA0, sA1, sB0, sB1;
    __builtin_amdgcn_s_setprio(1);
    sA0 = __builtin_amdgcn_mfma_f32_32x32x16_bf16(kf0, qfA0, (f32x16){}, 0, 0, 0);
    sA0 = __builtin_amdgcn_mfma_f32_32x32x16_bf16(kf1, qfA1, sA0, 0, 0, 0);
    sA1 = __builtin_amdgcn_mfma_f32_32x32x16_bf16(kf2, qfA0, (f32x16){}, 0, 0, 0);
    sA1 = __builtin_amdgcn_mfma_f32_32x32x16_bf16(kf3, qfA1, sA1, 0, 0, 0);
    sB0 = __builtin_amdgcn_mfma_f32_32x32x16_bf16(kf0, qfB0, (f32x16){}, 0, 0, 0);
    sB0 = __builtin_amdgcn_mfma_f32_32x32x16_bf16(kf1, qfB1, sB0, 0, 0, 0);
    sB1 = __builtin_amdgcn_mfma_f32_32x32x16_bf16(kf2, qfB0, (f32x16){}, 0, 0, 0);
    sB1 = __builtin_amdgcn_mfma_f32_32x32x16_bf16(kf3, qfB1, sB1, 0, 0, 0);
    __builtin_amdgcn_s_setprio(0);

    // P = exp2(S), packed; regs already in PV B-frag order
    u32 pwA[16] __attribute__((aligned(16)));
    u32 pwB[16] __attribute__((aligned(16)));
    #pragma unroll
    for (int r = 0; r < 16; r += 2) {
      pwA[r >> 1]       = e2pk(sA0[r], sA0[r + 1]);
      pwA[8 + (r >> 1)] = e2pk(sA1[r], sA1[r + 1]);
      pwB[r >> 1]       = e2pk(sB0[r], sB0[r + 1]);
      pwB[8 + (r >> 1)] = e2pk(sB1[r], sB1[r + 1]);
    }

    // O += V . P^T ; l += 1 . P^T   (V frags loaded once, reused by both q-tiles)
    __builtin_amdgcn_s_setprio(1);
    #pragma unroll
    for (int s = 0; s < 2; ++s) {
      #pragma unroll
      for (int kb = 0; kb < 2; ++kb) {
        const bf16x8 pfA = __builtin_bit_cast(bf16x8, *(const u32x4*)&pwA[s * 8 + kb * 4]);
        const bf16x8 pfB = __builtin_bit_cast(bf16x8, *(const u32x4*)&pwB[s * 8 + kb * 4]);
        const bf16x8 vf0 = *(const bf16x8*)&vbuf[cur][(s * 4 + kb * 2) * 1024 + lofs];
        const bf16x8 vf1 = *(const bf16x8*)&vbuf[cur][(s * 4 + kb * 2 + 1) * 1024 + lofs];
        accA0 = __builtin_amdgcn_mfma_f32_32x32x16_bf16(vf0, pfA, accA0, 0, 0, 0);
        accA1 = __builtin_amdgcn_mfma_f32_32x32x16_bf16(vf1, pfA, accA1, 0, 0, 0);
        accB0 = __builtin_amdgcn_mfma_f32_32x32x16_bf16(vf0, pfB, accB0, 0, 0, 0);
        accB1 = __builtin_amdgcn_mfma_f32_32x32x16_bf16(vf1, pfB, accB1, 0, 0, 0);
        laccA = __builtin_amdgcn_mfma_f32_32x32x16_bf16(onef, pfA, laccA, 0, 0, 0);
        laccB = __builtin_amdgcn_mfma_f32_32x32x16_bf16(onef, pfB, laccB, 0, 0, 0);
      }
    }
    __builtin_amdgcn_s_setprio(0);
  }

  // opart[(b,qt128)*NSPLIT+split][cp(32)][q(128)], bf16-packed channel pairs
  const int qt128 = qt * 2 + (wid >> 1);
  const size_t obase = ((size_t)(b * 32 + qt128) * NSPLIT + split) * 4096;
  #pragma unroll
  for (int j = 0; j < 2; ++j) {
    const int col = (wid & 1) * 64 + j * 32 + c31;
    #pragma unroll
    for (int ct = 0; ct < 2; ++ct) {
      const f32x16& a = j ? (ct ? accB1 : accB0) : (ct ? accA1 : accA0);
      #pragma unroll
      for (int g2 = 0; g2 < 4; ++g2) {
        #pragma unroll
        for (int b2 = 0; b2 < 2; ++b2) {
          int cp = ct * 16 + g2 * 4 + h * 2 + b2;
          float lo = a[g2 * 4 + b2 * 2], hi = a[g2 * 4 + b2 * 2 + 1];
          u32 pr; asm("v_cvt_pk_bf16_f32 %0, %1, %2" : "=v"(pr) : "v"(lo), "v"(hi));
          opart[obase + cp * 128 + col] = pr;
        }
      }
    }
    if (h == 0) {
      const f32x16& l = j ? laccB : laccA;
      lpart[((size_t)(b * 32 + qt128) * NSPLIT + split) * 128 + col] = l[0];
    }
  }
}

// ---- kernel 3: combine splits + normalize + fused final conv + residual
// 512 threads: 8 waves x 8 outputs (wave-uniform weights), 64 queries/block
template<int NSPLIT>
__global__ __launch_bounds__(512) void combine_kernel(
    const u32* __restrict__ opart, const float* __restrict__ lpart,
    const float* __restrict__ x, const float* __restrict__ wf, const float* __restrict__ bfb,
    const float* __restrict__ gamma, float* __restrict__ out)
{
  __shared__ float ols[64][65];
  __shared__ float linv[64];
  const int bid = blockIdx.x;
  const int b = bid & 7, qt64 = bid >> 3;
  const int qt128 = qt64 >> 1, qh = qt64 & 1;
  const int t = threadIdx.x, lane = t & 63, wid = t >> 6;

  const u32* ob = opart + (size_t)(b * 32 + qt128) * NSPLIT * 4096 + qh * 64;
  #pragma unroll
  for (int jj = 0; jj < 4; ++jj) {
    int i = t + 512 * jj;
    int cp = i >> 6, q = i & 63;
    float lo = 0.f, hi = 0.f;
    #pragma unroll
    for (int s = 0; s < NSPLIT; ++s) {
      u32 a = ob[s * 4096 + cp * 128 + q];
      lo += __builtin_bit_cast(float, (a << 16));
      hi += __builtin_bit_cast(float, (a & 0xffff0000u));
    }
    ols[cp * 2][q]     = lo;
    ols[cp * 2 + 1][q] = hi;
  }
  if (t < 64) {
    const float* lp = lpart + (size_t)(b * 32 + qt128) * NSPLIT * 128 + qh * 64;
    float l = 0.f;
    #pragma unroll
    for (int s = 0; s < NSPLIT; ++s) l += lp[s * 128 + t];
    linv[t] = 1.f / l;
  }
  __syncthreads();

  const float oinv = linv[lane];
  float oc[64];
  #pragma unroll
  for (int c = 0; c < 64; ++c) oc[c] = ols[c][lane] * oinv;
  const float gm = gamma[0];
  const size_t nidx = (size_t)qt64 * 64 + lane;
  #pragma unroll
  for (int i = 0; i < 8; ++i) {
    const int o = wid * 8 + i;
    float a = bfb[o];
    #pragma unroll
    for (int c = 0; c < 64; ++c) a = fmaf(wf[o * 64 + c], oc[c], a);
    const size_t idx = ((size_t)b * CCH + o) * NN + nidx;
    out[idx] = gm * a + x[idx];
  }
}

extern "C" void kernel_launch(void* const* d_in, const int* in_sizes, int n_in,
                              void* d_out, int out_size, void* d_ws, size_t ws_size,
                              hipStream_t stream) {
  const float* x     = (const float*)d_in[0];
  const float* wq    = (const float*)d_in[1];
  const float* bq    = (const float*)d_in[2];
  const float* wk    = (const float*)d_in[3];
  const float* bk    = (const float*)d_in[4];
  const float* wv    = (const float*)d_in[5];
  const float* bv    = (const float*)d_in[6];
  const float* wf    = (const float*)d_in[7];
  const float* bf_   = (const float*)d_in[8];
  const float* gamma = (const float*)d_in[9];
  float* out = (float*)d_out;

  u16* qT   = (u16*)d_ws;                                   // 2 MB
  char* kws = (char*)(qT + (size_t)8 * NN * CQ);            // 2 MB
  char* vws = kws + (size_t)8 * 64 * 4096;                  // 4 MB
  u32* opart = (u32*)(vws + (size_t)8 * 64 * 8192);
  const size_t base = 2097152ull + 2097152ull + 4194304ull;
  const size_t need4 = base + 4ull * (4194304ull + 131072ull);

  qkv_kernel<<<dim3(512), dim3(512), 0, stream>>>(x, wq, bq, wk, bk, wv, bv, qT, kws, vws);
  if (ws_size >= need4) {
    float* lpart = (float*)(opart + (size_t)8 * 32 * 4 * 4096);
    attn_kernel<4><<<dim3(512), dim3(256), 0, stream>>>(qT, kws, vws, opart, lpart);
    combine_kernel<4><<<dim3(512), dim3(512), 0, stream>>>(opart, lpart, x, wf, bf_, gamma, out);
  } else {
    float* lpart = (float*)(opart + (size_t)8 * 32 * 2 * 4096);
    attn_kernel<2><<<dim3(256), dim3(256), 0, stream>>>(qT, kws, vws, opart, lpart);
    combine_kernel<2><<<dim3(512), dim3(512), 0, stream>>>(opart, lpart, x, wf, bf_, gamma, out);
  }
}

// Round 9
// 89.812 us; speedup vs baseline: 1.0958x; 1.0024x over previous
//
#include <hip/hip_runtime.h>

typedef unsigned short u16;
typedef unsigned int   u32;
typedef __bf16  bf16x8 __attribute__((ext_vector_type(8)));
typedef float   f32x16 __attribute__((ext_vector_type(16)));
typedef u32     u32x4  __attribute__((ext_vector_type(4)));

#define NN  4096
#define CCH 64
#define CQ  32
#define K1S 0.0225421092623961f   // log2(e)/64  (folded into q)

__device__ __forceinline__ u16 bfc(float a) { return __builtin_bit_cast(u16, (__bf16)a); }

// exp2 + pack pair to bf16x2 in 3 instructions
__device__ __forceinline__ u32 e2pk(float a, float b) {
  float ea, eb; u32 r;
  asm("v_exp_f32 %0, %1" : "=v"(ea) : "v"(a));
  asm("v_exp_f32 %0, %1" : "=v"(eb) : "v"(b));
  asm("v_cvt_pk_bf16_f32 %0, %1, %2" : "=v"(r) : "v"(ea), "v"(eb));
  return r;
}

__device__ __forceinline__ void gload16(const void* g, void* l) {
  __builtin_amdgcn_global_load_lds((const __attribute__((address_space(1))) void*)g,
                                   (__attribute__((address_space(3))) void*)l, 16, 0, 0);
}

// Image layouts (per 64-key chunk), frag-major so attn LDS reads are lane-linear:
//  K image 4KB: region(s,ks)=s*2+ks (1KB); lane l=h*32+r31: K[key=s*32+r31][ck=ks*16+8h+{0..7}]
//  V image 8KB: region(s,kb,ct)=s*4+kb*2+ct (1KB); lane l: V[c=ct*32+r31][key=s*32+kb*16+4h+{0..3,8..11}]
// Consecutive chunks are contiguous -> a 128-key macro-chunk is 8KB K + 16KB V contiguous.

// ---- kernel 1: 1x1 convs; x tile staged ONCE in LDS
__global__ __launch_bounds__(512) void qkv_kernel(
    const float* __restrict__ x,
    const float* __restrict__ wq, const float* __restrict__ bq,
    const float* __restrict__ wk, const float* __restrict__ bk,
    const float* __restrict__ wv, const float* __restrict__ bv,
    u16* __restrict__ qT, char* __restrict__ kws, char* __restrict__ vws)
{
  __shared__ float xs[64][64];
  __shared__ u16 qls[64][34];
  __shared__ u16 kls[64][34];
  __shared__ u16 vls[64][66];
  const int bid = blockIdx.x;
  const int b = bid >> 6;
  const int chunk = bid & 63;
  const int nbase = chunk * 64;
  const int t = threadIdx.x, lane = t & 63, wid = t >> 6;

  {
    const float* xb = x + (size_t)b * CCH * NN + nbase;
    const int row = t >> 3, colq = (t & 7) * 2;
    float4 v0 = *(const float4*)(xb + (size_t)row * NN + colq * 4);
    float4 v1 = *(const float4*)(xb + (size_t)row * NN + colq * 4 + 4);
    float4* dst = (float4*)&xs[0][0];
    dst[row * 16 + colq]     = v0;
    dst[row * 16 + colq + 1] = v1;
  }
  __syncthreads();

  float xcol[64];
  #pragma unroll
  for (int c = 0; c < 64; ++c) xcol[c] = xs[c][lane];

  const float* w; const float* bias; float sc = 1.0f;
  const int sub = (wid & 1) * 16;
  if (wid < 2)      { w = wq + sub * 64; bias = bq + sub; sc = K1S; }
  else if (wid < 4) { w = wk + sub * 64; bias = bk + sub; }
  else              { w = wv + (wid - 4) * 16 * 64; bias = bv + (wid - 4) * 16; }

  #pragma unroll 2
  for (int i = 0; i < 16; ++i) {
    float a = bias[i];
    #pragma unroll
    for (int c = 0; c < 64; ++c) a = fmaf(w[i * 64 + c], xcol[c], a);
    a *= sc;
    u16 hv = bfc(a);
    if (wid < 2)      qls[lane][sub + i] = hv;
    else if (wid < 4) kls[lane][sub + i] = hv;
    else              vls[(wid - 4) * 16 + i][lane] = hv;
  }
  __syncthreads();

  u32* qdst = (u32*)(qT + ((size_t)b * NN + nbase) * CQ);
  #pragma unroll
  for (int jj = 0; jj < 2; ++jj) {
    int i = t + 512 * jj;
    int n = i >> 4, cp = i & 15;
    qdst[i] = *(const u32*)&qls[n][cp * 2];
  }
  u32* kimg = (u32*)(kws + ((size_t)b * 64 + chunk) * 4096);
  #pragma unroll
  for (int jj = 0; jj < 2; ++jj) {
    int i = t + 512 * jj;
    int reg = i >> 8, l = (i >> 2) & 63, j2 = i & 3;
    int s = reg >> 1, ks = reg & 1;
    int key = s * 32 + (l & 31);
    int ck  = ks * 16 + (l >> 5) * 8 + j2 * 2;
    kimg[i] = *(const u32*)&kls[key][ck];
  }
  u32* vimg = (u32*)(vws + ((size_t)b * 64 + chunk) * 8192);
  #pragma unroll
  for (int jj = 0; jj < 4; ++jj) {
    int i = t + 512 * jj;
    int reg = i >> 8, l = (i >> 2) & 63, j2 = i & 3;
    int s = reg >> 2, kb = (reg >> 1) & 1, ct = reg & 1;
    int c   = ct * 32 + (l & 31);
    int key = s * 32 + kb * 16 + (l >> 5) * 4 + (j2 >> 1) * 8 + (j2 & 1) * 2;
    vimg[i] = *(const u32*)&vls[c][key];
  }
}

// ---- kernel 2: flash attention; 128-key macro-chunks, tbuf, counted vmcnt, 8 barriers
template<int NSPLIT>
__global__ __launch_bounds__(256, 2) void attn_kernel(
    const u16* __restrict__ qT, const char* __restrict__ kws, const char* __restrict__ vws,
    u32* __restrict__ opart, float* __restrict__ lpart)
{
  constexpr int CH = 64 / NSPLIT;   // 64-key chunks per split
  constexpr int MH = CH / 2;        // 128-key macro-chunks
  __shared__ __align__(16) char kbuf[3][8192];
  __shared__ __align__(16) char vbuf[3][16384];
  const int bid = blockIdx.x;
  const int b = bid & 7, qt = (bid >> 3) & 15, split = bid >> 7;  // qt: 256-query tile
  const int t = threadIdx.x, lane = t & 63, wid = t >> 6;
  const int h = lane >> 5, c31 = lane & 31;

  // wave covers queries [qt*256 + wid*64, +64): tiles A (+0) and B (+32)
  const u16* qpA = qT + ((size_t)b * NN + qt * 256 + wid * 64 + c31) * CQ + h * 8;
  const bf16x8 qfA0 = *(const bf16x8*)(qpA);
  const bf16x8 qfA1 = *(const bf16x8*)(qpA + 16);
  const bf16x8 qfB0 = *(const bf16x8*)(qpA + 32 * CQ);
  const bf16x8 qfB1 = *(const bf16x8*)(qpA + 32 * CQ + 16);

  const char* ksrc = kws + ((size_t)b * 64 + split * CH) * 4096 + t * 16;
  const char* vsrc = vws + ((size_t)b * 64 + split * CH) * 8192 + t * 16;

  auto stage = [&](int buf, int m) {   // 128-key macro-chunk m: 8KB K + 16KB V
    const char* kc = ksrc + (size_t)m * 8192;
    const char* vc = vsrc + (size_t)m * 16384;
    gload16(kc,         &kbuf[buf][wid * 1024]);
    gload16(kc + 4096,  &kbuf[buf][4096 + wid * 1024]);
    gload16(vc,         &vbuf[buf][wid * 1024]);
    gload16(vc + 4096,  &vbuf[buf][4096 + wid * 1024]);
    gload16(vc + 8192,  &vbuf[buf][8192 + wid * 1024]);
    gload16(vc + 12288, &vbuf[buf][12288 + wid * 1024]);
  };

  const bf16x8 onef = __builtin_bit_cast(bf16x8,
      (u32x4){0x3F803F80u, 0x3F803F80u, 0x3F803F80u, 0x3F803F80u});

  f32x16 accA0 = {}, accA1 = {}, accB0 = {}, accB1 = {}, laccA = {}, laccB = {};
  const int lofs = lane * 16;

  stage(0, 0);
  stage(1, 1);

  #pragma unroll
  for (int m = 0; m < MH; ++m) {
    // wait own stage(m) loads (6 newest = stage(m+1) may stay in flight)
    if (m == MH - 1) asm volatile("s_waitcnt vmcnt(0)" ::: "memory");
    else             asm volatile("s_waitcnt vmcnt(6)" ::: "memory");
    __builtin_amdgcn_s_barrier();     // all waves' stage(m) complete; all done reading buf[(m+2)%3]
    __builtin_amdgcn_sched_barrier(0);
    if (m + 2 < MH) stage((m + 2) % 3, m + 2);
    const int cur = m % 3;

    #pragma unroll
    for (int sub = 0; sub < 2; ++sub) {
      const char* kb = &kbuf[cur][sub * 4096];
      const char* vb = &vbuf[cur][sub * 8192];

      // K frags loaded ONCE, reused by both q-tiles
      const bf16x8 kf0 = *(const bf16x8*)&kb[lofs];
      const bf16x8 kf1 = *(const bf16x8*)&kb[1024 + lofs];
      const bf16x8 kf2 = *(const bf16x8*)&kb[2048 + lofs];
      const bf16x8 kf3 = *(const bf16x8*)&kb[3072 + lofs];

      f32x16 sA0, sA1, sB0, sB1;
      __builtin_amdgcn_s_setprio(1);
      sA0 = __builtin_amdgcn_mfma_f32_32x32x16_bf16(kf0, qfA0, (f32x16){}, 0, 0, 0);
      sA0 = __builtin_amdgcn_mfma_f32_32x32x16_bf16(kf1, qfA1, sA0, 0, 0, 0);
      sA1 = __builtin_amdgcn_mfma_f32_32x32x16_bf16(kf2, qfA0, (f32x16){}, 0, 0, 0);
      sA1 = __builtin_amdgcn_mfma_f32_32x32x16_bf16(kf3, qfA1, sA1, 0, 0, 0);
      sB0 = __builtin_amdgcn_mfma_f32_32x32x16_bf16(kf0, qfB0, (f32x16){}, 0, 0, 0);
      sB0 = __builtin_amdgcn_mfma_f32_32x32x16_bf16(kf1, qfB1, sB0, 0, 0, 0);
      sB1 = __builtin_amdgcn_mfma_f32_32x32x16_bf16(kf2, qfB0, (f32x16){}, 0, 0, 0);
      sB1 = __builtin_amdgcn_mfma_f32_32x32x16_bf16(kf3, qfB1, sB1, 0, 0, 0);
      __builtin_amdgcn_s_setprio(0);

      // P = exp2(S), packed; regs already in PV B-frag order
      u32 pwA[16] __attribute__((aligned(16)));
      u32 pwB[16] __attribute__((aligned(16)));
      #pragma unroll
      for (int r = 0; r < 16; r += 2) {
        pwA[r >> 1]       = e2pk(sA0[r], sA0[r + 1]);
        pwA[8 + (r >> 1)] = e2pk(sA1[r], sA1[r + 1]);
        pwB[r >> 1]       = e2pk(sB0[r], sB0[r + 1]);
        pwB[8 + (r >> 1)] = e2pk(sB1[r], sB1[r + 1]);
      }

      // O += V . P^T ; l += 1 . P^T   (V frags loaded once, reused by both q-tiles)
      __builtin_amdgcn_s_setprio(1);
      #pragma unroll
      for (int s = 0; s < 2; ++s) {
        #pragma unroll
        for (int kb2 = 0; kb2 < 2; ++kb2) {
          const bf16x8 pfA = __builtin_bit_cast(bf16x8, *(const u32x4*)&pwA[s * 8 + kb2 * 4]);
          const bf16x8 pfB = __builtin_bit_cast(bf16x8, *(const u32x4*)&pwB[s * 8 + kb2 * 4]);
          const bf16x8 vf0 = *(const bf16x8*)&vb[(s * 4 + kb2 * 2) * 1024 + lofs];
          const bf16x8 vf1 = *(const bf16x8*)&vb[(s * 4 + kb2 * 2 + 1) * 1024 + lofs];
          accA0 = __builtin_amdgcn_mfma_f32_32x32x16_bf16(vf0, pfA, accA0, 0, 0, 0);
          accA1 = __builtin_amdgcn_mfma_f32_32x32x16_bf16(vf1, pfA, accA1, 0, 0, 0);
          accB0 = __builtin_amdgcn_mfma_f32_32x32x16_bf16(vf0, pfB, accB0, 0, 0, 0);
          accB1 = __builtin_amdgcn_mfma_f32_32x32x16_bf16(vf1, pfB, accB1, 0, 0, 0);
          laccA = __builtin_amdgcn_mfma_f32_32x32x16_bf16(onef, pfA, laccA, 0, 0, 0);
          laccB = __builtin_amdgcn_mfma_f32_32x32x16_bf16(onef, pfB, laccB, 0, 0, 0);
        }
      }
      __builtin_amdgcn_s_setprio(0);
    }
  }

  // opart[(b,qt128)*NSPLIT+split][cp(32)][q(128)], bf16-packed channel pairs
  const int qt128 = qt * 2 + (wid >> 1);
  const size_t obase = ((size_t)(b * 32 + qt128) * NSPLIT + split) * 4096;
  #pragma unroll
  for (int j = 0; j < 2; ++j) {
    const int col = (wid & 1) * 64 + j * 32 + c31;
    #pragma unroll
    for (int ct = 0; ct < 2; ++ct) {
      const f32x16& a = j ? (ct ? accB1 : accB0) : (ct ? accA1 : accA0);
      #pragma unroll
      for (int g2 = 0; g2 < 4; ++g2) {
        #pragma unroll
        for (int b2 = 0; b2 < 2; ++b2) {
          int cp = ct * 16 + g2 * 4 + h * 2 + b2;
          float lo = a[g2 * 4 + b2 * 2], hi = a[g2 * 4 + b2 * 2 + 1];
          u32 pr; asm("v_cvt_pk_bf16_f32 %0, %1, %2" : "=v"(pr) : "v"(lo), "v"(hi));
          opart[obase + cp * 128 + col] = pr;
        }
      }
    }
    if (h == 0) {
      const f32x16& l = j ? laccB : laccA;
      lpart[((size_t)(b * 32 + qt128) * NSPLIT + split) * 128 + col] = l[0];
    }
  }
}

// ---- kernel 3: combine splits + normalize + fused final conv + residual
template<int NSPLIT>
__global__ __launch_bounds__(512) void combine_kernel(
    const u32* __restrict__ opart, const float* __restrict__ lpart,
    const float* __restrict__ x, const float* __restrict__ wf, const float* __restrict__ bfb,
    const float* __restrict__ gamma, float* __restrict__ out)
{
  __shared__ float ols[64][65];
  __shared__ float linv[64];
  const int bid = blockIdx.x;
  const int b = bid & 7, qt64 = bid >> 3;
  const int qt128 = qt64 >> 1, qh = qt64 & 1;
  const int t = threadIdx.x, lane = t & 63, wid = t >> 6;

  const u32* ob = opart + (size_t)(b * 32 + qt128) * NSPLIT * 4096 + qh * 64;
  #pragma unroll
  for (int jj = 0; jj < 4; ++jj) {
    int i = t + 512 * jj;
    int cp = i >> 6, q = i & 63;
    float lo = 0.f, hi = 0.f;
    #pragma unroll
    for (int s = 0; s < NSPLIT; ++s) {
      u32 a = ob[s * 4096 + cp * 128 + q];
      lo += __builtin_bit_cast(float, (a << 16));
      hi += __builtin_bit_cast(float, (a & 0xffff0000u));
    }
    ols[cp * 2][q]     = lo;
    ols[cp * 2 + 1][q] = hi;
  }
  if (t < 64) {
    const float* lp = lpart + (size_t)(b * 32 + qt128) * NSPLIT * 128 + qh * 64;
    float l = 0.f;
    #pragma unroll
    for (int s = 0; s < NSPLIT; ++s) l += lp[s * 128 + t];
    linv[t] = 1.f / l;
  }
  __syncthreads();

  const float oinv = linv[lane];
  float oc[64];
  #pragma unroll
  for (int c = 0; c < 64; ++c) oc[c] = ols[c][lane] * oinv;
  const float gm = gamma[0];
  const size_t nidx = (size_t)qt64 * 64 + lane;
  #pragma unroll
  for (int i = 0; i < 8; ++i) {
    const int o = wid * 8 + i;
    float a = bfb[o];
    #pragma unroll
    for (int c = 0; c < 64; ++c) a = fmaf(wf[o * 64 + c], oc[c], a);
    const size_t idx = ((size_t)b * CCH + o) * NN + nidx;
    out[idx] = gm * a + x[idx];
  }
}

extern "C" void kernel_launch(void* const* d_in, const int* in_sizes, int n_in,
                              void* d_out, int out_size, void* d_ws, size_t ws_size,
                              hipStream_t stream) {
  const float* x     = (const float*)d_in[0];
  const float* wq    = (const float*)d_in[1];
  const float* bq    = (const float*)d_in[2];
  const float* wk    = (const float*)d_in[3];
  const float* bk    = (const float*)d_in[4];
  const float* wv    = (const float*)d_in[5];
  const float* bv    = (const float*)d_in[6];
  const float* wf    = (const float*)d_in[7];
  const float* bf_   = (const float*)d_in[8];
  const float* gamma = (const float*)d_in[9];
  float* out = (float*)d_out;

  u16* qT   = (u16*)d_ws;                                   // 2 MB
  char* kws = (char*)(qT + (size_t)8 * NN * CQ);            // 2 MB
  char* vws = kws + (size_t)8 * 64 * 4096;                  // 4 MB
  u32* opart = (u32*)(vws + (size_t)8 * 64 * 8192);
  const size_t base = 2097152ull + 2097152ull + 4194304ull;
  const size_t need4 = base + 4ull * (4194304ull + 131072ull);

  qkv_kernel<<<dim3(512), dim3(512), 0, stream>>>(x, wq, bq, wk, bk, wv, bv, qT, kws, vws);
  if (ws_size >= need4) {
    float* lpart = (float*)(opart + (size_t)8 * 32 * 4 * 4096);
    attn_kernel<4><<<dim3(512), dim3(256), 0, stream>>>(qT, kws, vws, opart, lpart);
    combine_kernel<4><<<dim3(512), dim3(512), 0, stream>>>(opart, lpart, x, wf, bf_, gamma, out);
  } else {
    float* lpart = (float*)(opart + (size_t)8 * 32 * 2 * 4096);
    attn_kernel<2><<<dim3(256), dim3(256), 0, stream>>>(qT, kws, vws, opart, lpart);
    combine_kernel<2><<<dim3(512), dim3(512), 0, stream>>>(opart, lpart, x, wf, bf_, gamma, out);
  }
}